// Round 2
// baseline (197.085 us; speedup 1.0000x reference)
//
#include <hip/hip_runtime.h>
#include <math.h>

#define BATCH 4
#define CH    96
#define HH    48
#define WW    48
#define HWPIX (HH*WW)         // 2304
#define NPIX  (BATCH*HWPIX)   // 9216
#define WIN   13
#define WIN2  169
#define HALF  6
#define TOPK  8
#define NEGV  (-1000000000.0f)

// ---------------------------------------------------------------------------
// K1: transpose x (B,C,HW) -> xt (B*HW, C) [stored in d_out as scratch],
//     compute per-pixel invnorm / mean / rstd
// ---------------------------------------------------------------------------
__global__ __launch_bounds__(256) void k1_prep(
    const float* __restrict__ x, float* __restrict__ xt,
    float* __restrict__ invn, float* __restrict__ muv, float* __restrict__ rsd)
{
    __shared__ float lds[96][65];  // pad 65 -> conflict-free both phases
    int bid = blockIdx.x;          // 144 = 4 batches * 36 tiles
    int b   = bid / 36;
    int p0  = (bid % 36) * 64;
    int t   = threadIdx.x;

    // load 96 C x 64 pixels, coalesced over pixels
    #pragma unroll
    for (int it = 0; it < 24; ++it) {
        int e = t + it * 256;
        int c = e >> 6;
        int p = e & 63;
        lds[c][p] = x[(b * CH + c) * HWPIX + p0 + p];
    }
    __syncthreads();

    if (t < 64) {
        float s = 0.f, ss = 0.f;
        #pragma unroll
        for (int c = 0; c < CH; ++c) {
            float v = lds[c][t];
            s += v; ss += v * v;
        }
        int gp = b * HWPIX + p0 + t;
        float nrm = sqrtf(ss);
        invn[gp] = 1.0f / fmaxf(nrm, 1e-12f);
        float m = s * (1.0f / 96.0f);
        muv[gp] = m;
        float var = ss * (1.0f / 96.0f) - m * m;
        rsd[gp] = 1.0f / sqrtf(var + 1e-5f);
    }

    // write xt pixel-major, coalesced over channels
    #pragma unroll
    for (int it = 0; it < 24; ++it) {
        int e = t + it * 256;
        int p = e / 96;
        int c = e - p * 96;
        xt[(b * HWPIX + p0 + p) * CH + c] = lds[c][p];
    }
}

// ---------------------------------------------------------------------------
// K2: per-pixel (one wave): sims over 169 window, top-8, softmax, aggregate,
//     add LayerNorm -> enh (B*HW, C)
// ---------------------------------------------------------------------------
__global__ __launch_bounds__(256) void k2_knn(
    const float* __restrict__ xt, const float* __restrict__ invn,
    const float* __restrict__ muv, const float* __restrict__ rsd,
    const float* __restrict__ lnw, const float* __restrict__ lnb,
    float* __restrict__ enh)
{
    __shared__ float own[4][96];
    int wv   = threadIdx.x >> 6;
    int lane = threadIdx.x & 63;
    int gp   = blockIdx.x * 4 + wv;     // 2304 blocks * 4 pixels
    int b    = gp / HWPIX;
    int p    = gp - b * HWPIX;
    int py   = p / WW;
    int px   = p - py * WW;

    // stage own feature vector into LDS (broadcast source for dots)
    own[wv][lane] = xt[gp * CH + lane];
    if (lane < 32) own[wv][lane + 64] = xt[gp * CH + lane + 64];
    float inp = invn[gp];
    __syncthreads();

    // each lane: up to 3 neighbors (n = lane, lane+64, lane+128)
    float s0 = -2e9f, s1 = -2e9f, s2 = -2e9f;
    const float4* ov = (const float4*)(own[wv]);
    #pragma unroll
    for (int k = 0; k < 3; ++k) {
        int n = lane + 64 * k;
        float sim = -2e9f;
        if (n < WIN2) {
            int dy = n / WIN - HALF;
            int dx = n - (dy + HALF) * WIN - HALF;
            int ny = py + dy, nx = px + dx;
            if (ny >= 0 && ny < HH && nx >= 0 && nx < WW) {
                int q = b * HWPIX + ny * WW + nx;
                float inq = invn[q];
                const float4* qv = (const float4*)(xt + q * CH);
                float ax = 0.f, ay = 0.f, az = 0.f, aw = 0.f;
                #pragma unroll
                for (int c4 = 0; c4 < 24; ++c4) {
                    float4 a = ov[c4];
                    float4 bb = qv[c4];
                    ax += a.x * bb.x; ay += a.y * bb.y;
                    az += a.z * bb.z; aw += a.w * bb.w;
                }
                sim = ((ax + ay) + (az + aw)) * inp * inq;
            } else {
                sim = NEGV;
            }
        }
        if (k == 0) s0 = sim; else if (k == 1) s1 = sim; else s2 = sim;
    }

    // iterative top-8 with lax.top_k tie-breaking (equal value -> lower index)
    float topv[TOPK];
    int   topn[TOPK];
    #pragma unroll
    for (int r = 0; r < TOPK; ++r) {
        float v = s0; int n = lane;
        if (s1 > v) { v = s1; n = lane + 64; }
        if (s2 > v) { v = s2; n = lane + 128; }
        #pragma unroll
        for (int off = 1; off < 64; off <<= 1) {
            float ovv = __shfl_xor(v, off);
            int   onn = __shfl_xor(n, off);
            if (ovv > v || (ovv == v && onn < n)) { v = ovv; n = onn; }
        }
        topv[r] = v; topn[r] = n;
        bool mine = (n & 63) == lane;
        int  k = n >> 6;
        s0 = (mine && k == 0) ? -2e9f : s0;
        s1 = (mine && k == 1) ? -2e9f : s1;
        s2 = (mine && k == 2) ? -2e9f : s2;
    }

    // softmax weights + neighbor global indices (uniform across wave)
    float wts[TOPK]; int qidx[TOPK];
    float wsum = 0.f;
    #pragma unroll
    for (int r = 0; r < TOPK; ++r) {
        float e = expf(topv[r] - topv[0]);
        wts[r] = e; wsum += e;
        int n = topn[r];
        int dy = n / WIN - HALF;
        int dx = n - (dy + HALF) * WIN - HALF;
        qidx[r] = b * HWPIX + (py + dy) * WW + (px + dx);
    }
    float winv = 1.0f / wsum;

    // aggregate raw features + LayerNorm, write enh
    float m = muv[gp], rs = rsd[gp];
    {
        int c = lane;
        float a = 0.f;
        #pragma unroll
        for (int r = 0; r < TOPK; ++r) a += wts[r] * xt[qidx[r] * CH + c];
        a *= winv;
        float e = a + (own[wv][c] - m) * rs * lnw[c] + lnb[c];
        enh[gp * CH + c] = e;
    }
    if (lane < 32) {
        int c = lane + 64;
        float a = 0.f;
        #pragma unroll
        for (int r = 0; r < TOPK; ++r) a += wts[r] * xt[qidx[r] * CH + c];
        a *= winv;
        float e = a + (own[wv][c] - m) * rs * lnw[c] + lnb[c];
        enh[gp * CH + c] = e;
    }
}

// ---------------------------------------------------------------------------
// K3: fused FFN: h = relu(enh @ w1^T + b1) staged in LDS;
//     out = enh + (h @ w2^T + b2), written in (B,C,H,W) layout into d_out.
//     One block = 64 pixels; h tile = [192][64] in LDS.
// ---------------------------------------------------------------------------
__global__ __launch_bounds__(256) void k3_ffn(
    const float* __restrict__ enh, const float* __restrict__ w1,
    const float* __restrict__ b1, const float* __restrict__ w2,
    const float* __restrict__ b2, float* __restrict__ out)
{
    __shared__ float hl[192][66];   // 50688 B, 2-way bank alias only
    int g    = blockIdx.x;          // 144 = 4 batches * 36 tiles
    int b    = g / 36;
    int p0   = (g % 36) * 64;
    int wv   = threadIdx.x >> 6;
    int lane = threadIdx.x & 63;
    int gp   = b * HWPIX + p0 + lane;

    // own enhanced row in registers (96 floats as 24 float4)
    float4 ereg[24];
    const float4* ev = (const float4*)(enh + gp * CH);
    #pragma unroll
    for (int c4 = 0; c4 < 24; ++c4) ereg[c4] = ev[c4];

    // phase A: each wave computes 48 of the 192 hidden units for all 64 pixels
    const float4* w1v = (const float4*)w1;
    int jbase = wv * 48;
    #pragma unroll 4
    for (int jj = 0; jj < 48; ++jj) {
        int j = jbase + jj;
        float acc = b1[j];                 // wave-uniform -> scalar load
        #pragma unroll
        for (int c4 = 0; c4 < 24; ++c4) {
            float4 w4 = w1v[j * 24 + c4];  // wave-uniform -> s_load_dwordx4
            acc += ereg[c4].x * w4.x + ereg[c4].y * w4.y
                 + ereg[c4].z * w4.z + ereg[c4].w * w4.w;
        }
        hl[j][lane] = fmaxf(acc, 0.f);
    }
    __syncthreads();

    // phase B: each wave produces 24 output channels for all 64 pixels
    int cbase = wv * 24;
    float acc[24];
    #pragma unroll
    for (int cc = 0; cc < 24; ++cc) acc[cc] = 0.f;

    #pragma unroll 2
    for (int j = 0; j < 192; ++j) {
        float hv = hl[j][lane];
        #pragma unroll
        for (int cc = 0; cc < 24; ++cc)
            acc[cc] += hv * w2[(cbase + cc) * 192 + j];  // uniform -> s_load
    }

    #pragma unroll
    for (int cc = 0; cc < 24; ++cc) {
        int c = cbase + cc;
        out[(b * CH + c) * HWPIX + p0 + lane] =
            enh[gp * CH + c] + acc[cc] + b2[c];          // coalesced store
    }
}

// ---------------------------------------------------------------------------
extern "C" void kernel_launch(void* const* d_in, const int* in_sizes, int n_in,
                              void* d_out, int out_size, void* d_ws, size_t ws_size,
                              hipStream_t stream)
{
    const float* x   = (const float*)d_in[0];
    const float* w1  = (const float*)d_in[1];
    const float* b1  = (const float*)d_in[2];
    const float* w2  = (const float*)d_in[3];
    const float* b2  = (const float*)d_in[4];
    const float* lnw = (const float*)d_in[5];
    const float* lnb = (const float*)d_in[6];
    float* out = (float*)d_out;

    // xt lives in d_out (exactly NPIX*CH floats): k1 writes it, k2 consumes it,
    // k3 then overwrites d_out with the final output. Stream-ordered, no alias
    // within any single kernel.
    float* xt = out;

    // workspace: enh + 3 small per-pixel arrays = 3,649,536 bytes total
    float* ws   = (float*)d_ws;
    float* enh  = ws;                        // NPIX*96 = 884736
    float* invn = enh + NPIX * CH;           // NPIX
    float* muv  = invn + NPIX;               // NPIX
    float* rsd  = muv + NPIX;                // NPIX

    hipLaunchKernelGGL(k1_prep, dim3(144), dim3(256), 0, stream,
                       x, xt, invn, muv, rsd);
    hipLaunchKernelGGL(k2_knn, dim3(NPIX / 4), dim3(256), 0, stream,
                       xt, invn, muv, rsd, lnw, lnb, enh);
    hipLaunchKernelGGL(k3_ffn, dim3(144), dim3(256), 0, stream,
                       enh, w1, b1, w2, b2, out);
}

// Round 3
// 146.238 us; speedup vs baseline: 1.3477x; 1.3477x over previous
//
#include <hip/hip_runtime.h>
#include <math.h>

#define BATCH 4
#define CH    96
#define HH    48
#define WW    48
#define HWPIX (HH*WW)         // 2304
#define NPIX  (BATCH*HWPIX)   // 9216
#define WIN   13
#define WIN2  169
#define HALF  6
#define TOPK  8
#define NEGV  (-1000000000.0f)

// ---------------------------------------------------------------------------
// K1: transpose x (B,C,HW) -> xt (B*HW, C) [stored in d_out as scratch],
//     compute per-pixel invnorm / mean / rstd
// ---------------------------------------------------------------------------
__global__ __launch_bounds__(256) void k1_prep(
    const float* __restrict__ x, float* __restrict__ xt,
    float* __restrict__ invn, float* __restrict__ muv, float* __restrict__ rsd)
{
    __shared__ float lds[96][65];  // pad 65 -> conflict-free both phases
    int bid = blockIdx.x;          // 144 = 4 batches * 36 tiles
    int b   = bid / 36;
    int p0  = (bid % 36) * 64;
    int t   = threadIdx.x;

    // load 96 C x 64 pixels, coalesced over pixels
    #pragma unroll
    for (int it = 0; it < 24; ++it) {
        int e = t + it * 256;
        int c = e >> 6;
        int p = e & 63;
        lds[c][p] = x[(b * CH + c) * HWPIX + p0 + p];
    }
    __syncthreads();

    if (t < 64) {
        float s = 0.f, ss = 0.f;
        #pragma unroll
        for (int c = 0; c < CH; ++c) {
            float v = lds[c][t];
            s += v; ss += v * v;
        }
        int gp = b * HWPIX + p0 + t;
        float nrm = sqrtf(ss);
        invn[gp] = 1.0f / fmaxf(nrm, 1e-12f);
        float m = s * (1.0f / 96.0f);
        muv[gp] = m;
        float var = ss * (1.0f / 96.0f) - m * m;
        rsd[gp] = 1.0f / sqrtf(var + 1e-5f);
    }

    // write xt pixel-major, coalesced over channels
    #pragma unroll
    for (int it = 0; it < 24; ++it) {
        int e = t + it * 256;
        int p = e / 96;
        int c = e - p * 96;
        xt[(b * HWPIX + p0 + p) * CH + c] = lds[c][p];
    }
}

// ---------------------------------------------------------------------------
// K2: per-pixel (one wave): sims over 169 window, top-8, softmax, aggregate,
//     add LayerNorm -> enh (B*HW, C)
// ---------------------------------------------------------------------------
__global__ __launch_bounds__(256) void k2_knn(
    const float* __restrict__ xt, const float* __restrict__ invn,
    const float* __restrict__ muv, const float* __restrict__ rsd,
    const float* __restrict__ lnw, const float* __restrict__ lnb,
    float* __restrict__ enh)
{
    __shared__ float own[4][96];
    int wv   = threadIdx.x >> 6;
    int lane = threadIdx.x & 63;
    int gp   = blockIdx.x * 4 + wv;     // 2304 blocks * 4 pixels
    int b    = gp / HWPIX;
    int p    = gp - b * HWPIX;
    int py   = p / WW;
    int px   = p - py * WW;

    // stage own feature vector into LDS (broadcast source for dots)
    own[wv][lane] = xt[gp * CH + lane];
    if (lane < 32) own[wv][lane + 64] = xt[gp * CH + lane + 64];
    float inp = invn[gp];
    __syncthreads();

    // each lane: up to 3 neighbors (n = lane, lane+64, lane+128)
    float s0 = -2e9f, s1 = -2e9f, s2 = -2e9f;
    const float4* ov = (const float4*)(own[wv]);
    #pragma unroll
    for (int k = 0; k < 3; ++k) {
        int n = lane + 64 * k;
        float sim = -2e9f;
        if (n < WIN2) {
            int dy = n / WIN - HALF;
            int dx = n - (dy + HALF) * WIN - HALF;
            int ny = py + dy, nx = px + dx;
            if (ny >= 0 && ny < HH && nx >= 0 && nx < WW) {
                int q = b * HWPIX + ny * WW + nx;
                float inq = invn[q];
                const float4* qv = (const float4*)(xt + q * CH);
                float ax = 0.f, ay = 0.f, az = 0.f, aw = 0.f;
                #pragma unroll
                for (int c4 = 0; c4 < 24; ++c4) {
                    float4 a = ov[c4];
                    float4 bb = qv[c4];
                    ax += a.x * bb.x; ay += a.y * bb.y;
                    az += a.z * bb.z; aw += a.w * bb.w;
                }
                sim = ((ax + ay) + (az + aw)) * inp * inq;
            } else {
                sim = NEGV;
            }
        }
        if (k == 0) s0 = sim; else if (k == 1) s1 = sim; else s2 = sim;
    }

    // iterative top-8 with lax.top_k tie-breaking (equal value -> lower index)
    float topv[TOPK];
    int   topn[TOPK];
    #pragma unroll
    for (int r = 0; r < TOPK; ++r) {
        float v = s0; int n = lane;
        if (s1 > v) { v = s1; n = lane + 64; }
        if (s2 > v) { v = s2; n = lane + 128; }
        #pragma unroll
        for (int off = 1; off < 64; off <<= 1) {
            float ovv = __shfl_xor(v, off);
            int   onn = __shfl_xor(n, off);
            if (ovv > v || (ovv == v && onn < n)) { v = ovv; n = onn; }
        }
        topv[r] = v; topn[r] = n;
        bool mine = (n & 63) == lane;
        int  k = n >> 6;
        s0 = (mine && k == 0) ? -2e9f : s0;
        s1 = (mine && k == 1) ? -2e9f : s1;
        s2 = (mine && k == 2) ? -2e9f : s2;
    }

    // softmax weights + neighbor global indices (uniform across wave)
    float wts[TOPK]; int qidx[TOPK];
    float wsum = 0.f;
    #pragma unroll
    for (int r = 0; r < TOPK; ++r) {
        float e = expf(topv[r] - topv[0]);
        wts[r] = e; wsum += e;
        int n = topn[r];
        int dy = n / WIN - HALF;
        int dx = n - (dy + HALF) * WIN - HALF;
        qidx[r] = b * HWPIX + (py + dy) * WW + (px + dx);
    }
    float winv = 1.0f / wsum;

    // aggregate raw features + LayerNorm, write enh
    float m = muv[gp], rs = rsd[gp];
    {
        int c = lane;
        float a = 0.f;
        #pragma unroll
        for (int r = 0; r < TOPK; ++r) a += wts[r] * xt[qidx[r] * CH + c];
        a *= winv;
        float e = a + (own[wv][c] - m) * rs * lnw[c] + lnb[c];
        enh[gp * CH + c] = e;
    }
    if (lane < 32) {
        int c = lane + 64;
        float a = 0.f;
        #pragma unroll
        for (int r = 0; r < TOPK; ++r) a += wts[r] * xt[qidx[r] * CH + c];
        a *= winv;
        float e = a + (own[wv][c] - m) * rs * lnw[c] + lnb[c];
        enh[gp * CH + c] = e;
    }
}

// ---------------------------------------------------------------------------
// K3: fused FFN, high-occupancy version.
//     16 pixels per block, 576 blocks, 256 threads.
//     lane = pix + 16*sub; grp = wv*4+sub in [0,16).
//     Phase A: lane computes 12 hidden units (j = grp*12+jj) for its pixel.
//     Phase B: lane computes 6 out channels (c = grp*6+cc) for its pixel.
// ---------------------------------------------------------------------------
__global__ __launch_bounds__(256) void k3_ffn(
    const float* __restrict__ enh, const float* __restrict__ w1,
    const float* __restrict__ b1, const float* __restrict__ w2,
    const float* __restrict__ b2, float* __restrict__ out)
{
    __shared__ float hl[16][196];   // 12.5 KB; row stride 784 B (16B-aligned)
    int g    = blockIdx.x;          // 576 = 4 batches * 144 tiles
    int b    = g / 144;
    int p0   = (g % 144) * 16;
    int t    = threadIdx.x;
    int wv   = t >> 6;
    int lane = t & 63;
    int pix  = lane & 15;
    int sub  = lane >> 4;           // 0..3
    int grp  = wv * 4 + sub;        // 0..15
    int gp   = b * HWPIX + p0 + pix;

    // own enhanced row in registers (96 floats as 24 float4)
    float4 ereg[24];
    const float4* ev = (const float4*)(enh + gp * CH);
    #pragma unroll
    for (int c4 = 0; c4 < 24; ++c4) ereg[c4] = ev[c4];

    // phase A: 12 hidden units per lane
    const float4* w1v = (const float4*)w1;
    #pragma unroll 3
    for (int jj = 0; jj < 12; ++jj) {
        int j = grp * 12 + jj;
        float ax = 0.f, ay = 0.f, az = 0.f, aw = 0.f;
        #pragma unroll
        for (int c4 = 0; c4 < 24; ++c4) {
            float4 w4 = w1v[j * 24 + c4];
            ax += ereg[c4].x * w4.x; ay += ereg[c4].y * w4.y;
            az += ereg[c4].z * w4.z; aw += ereg[c4].w * w4.w;
        }
        hl[pix][j] = fmaxf(((ax + ay) + (az + aw)) + b1[j], 0.f);
    }
    __syncthreads();

    // phase B: 6 output channels per lane
    const float4* w2v = (const float4*)w2;
    const float4* hv4 = (const float4*)(&hl[pix][0]);
    float a0 = 0.f, a1 = 0.f, a2 = 0.f, a3 = 0.f, a4 = 0.f, a5 = 0.f;
    int c0 = grp * 6;
    #pragma unroll 4
    for (int j4 = 0; j4 < 48; ++j4) {
        float4 hv = hv4[j4];
        float4 q0 = w2v[(c0 + 0) * 48 + j4];
        float4 q1 = w2v[(c0 + 1) * 48 + j4];
        float4 q2 = w2v[(c0 + 2) * 48 + j4];
        float4 q3 = w2v[(c0 + 3) * 48 + j4];
        float4 q4 = w2v[(c0 + 4) * 48 + j4];
        float4 q5 = w2v[(c0 + 5) * 48 + j4];
        a0 += hv.x*q0.x + hv.y*q0.y + hv.z*q0.z + hv.w*q0.w;
        a1 += hv.x*q1.x + hv.y*q1.y + hv.z*q1.z + hv.w*q1.w;
        a2 += hv.x*q2.x + hv.y*q2.y + hv.z*q2.z + hv.w*q2.w;
        a3 += hv.x*q3.x + hv.y*q3.y + hv.z*q3.z + hv.w*q3.w;
        a4 += hv.x*q4.x + hv.y*q4.y + hv.z*q4.z + hv.w*q4.w;
        a5 += hv.x*q5.x + hv.y*q5.y + hv.z*q5.z + hv.w*q5.w;
    }

    float accs[6] = {a0, a1, a2, a3, a4, a5};
    #pragma unroll
    for (int cc = 0; cc < 6; ++cc) {
        int c = c0 + cc;
        out[(b * CH + c) * HWPIX + p0 + pix] =
            enh[gp * CH + c] + accs[cc] + b2[c];
    }
}

// ---------------------------------------------------------------------------
extern "C" void kernel_launch(void* const* d_in, const int* in_sizes, int n_in,
                              void* d_out, int out_size, void* d_ws, size_t ws_size,
                              hipStream_t stream)
{
    const float* x   = (const float*)d_in[0];
    const float* w1  = (const float*)d_in[1];
    const float* b1  = (const float*)d_in[2];
    const float* w2  = (const float*)d_in[3];
    const float* b2  = (const float*)d_in[4];
    const float* lnw = (const float*)d_in[5];
    const float* lnb = (const float*)d_in[6];
    float* out = (float*)d_out;

    // xt lives in d_out (exactly NPIX*CH floats): k1 writes it, k2 consumes it,
    // k3 then overwrites d_out with the final output. Stream-ordered, no alias
    // within any single kernel.
    float* xt = out;

    // workspace: enh + 3 small per-pixel arrays = 3,649,536 bytes total
    float* ws   = (float*)d_ws;
    float* enh  = ws;                        // NPIX*96 = 884736
    float* invn = enh + NPIX * CH;           // NPIX
    float* muv  = invn + NPIX;               // NPIX
    float* rsd  = muv + NPIX;                // NPIX

    hipLaunchKernelGGL(k1_prep, dim3(144), dim3(256), 0, stream,
                       x, xt, invn, muv, rsd);
    hipLaunchKernelGGL(k2_knn, dim3(NPIX / 4), dim3(256), 0, stream,
                       xt, invn, muv, rsd, lnw, lnb, enh);
    hipLaunchKernelGGL(k3_ffn, dim3(576), dim3(256), 0, stream,
                       enh, w1, b1, w2, b2, out);
}